// Round 3
// baseline (663.751 us; speedup 1.0000x reference)
//
#include <hip/hip_runtime.h>

// ConvLSTM B=8,T=16,CIN=16,HID=64,H=W=64,K=3 'SAME' — 16-launch bf16 MFMA.
// Round-6: revert round-5 (16-wave single block regressed: 2x B-issue volume,
// lockstep barrier). New structure: 512 blocks x 256 thr, ONE y-row per block,
// 4 waves of M_wave=64 (keeps 4 MFMA per B-load) -> 2 independent blocks/CU so
// staging of one block overlaps K-loop of the other. Targeted zero-init
// (only ch80..95 + halo cols + OOB rows; disjoint from staged region) kills
// the full-LDS zero pass and one barrier. Epilogue c reads issued BEFORE the
// K-loop (latency hides under 27 MFMA iters).

#define B_ 8
#define T_ 16
#define CIN_ 16
#define HID_ 64
#define H_ 64
#define W_ 64
#define HW_ (H_*W_)
#define CTOT_ 80
#define XS_ROW 66                  // 64 px + 2 halo
#define XS_CH 104                  // 96 K-channels + 8 pad
#define XS_SIZE (3*XS_ROW*XS_CH)   // 20592 hw = 41184 B
#define CSTRIDE_ (B_*HID_*HW_)     // 2097152

typedef __attribute__((ext_vector_type(8))) short short8;
typedef __attribute__((ext_vector_type(4))) float f32x4;

__device__ __forceinline__ unsigned short f2bf(float f){
    unsigned u = __float_as_uint(f);
    u = (u + 0x7FFFu + ((u >> 16) & 1u)) >> 16;   // RNE
    return (unsigned short)u;
}
__device__ __forceinline__ float sigm_(float v){ return 1.0f/(1.0f + __expf(-v)); }
__device__ __forceinline__ float tanh_(float v){ return 2.0f/(1.0f + __expf(-2.0f*v)) - 1.0f; }

// Wfrag: [tap 9][cc 3][ng 16] frags of 512 hw ([lane][j]).
// n = ng*16+(lane&15): g=n>>6, o=n&63; k-ch c = cc*32+(lane>>4)*8+j.
// Bias folded at c==80 (constant-1 A channel), center tap only.
__global__ void prep_wfrag(const float* __restrict__ Wf, const float* __restrict__ Wi,
                           const float* __restrict__ Wc, const float* __restrict__ Wo,
                           const float* __restrict__ bf, const float* __restrict__ bi,
                           const float* __restrict__ bc, const float* __restrict__ bo,
                           unsigned short* __restrict__ Wfrag){
    int idx = blockIdx.x*256 + threadIdx.x;          // 864*256 = 221184 exact
    int j    = idx & 7;
    int lane = (idx >> 3) & 63;
    int frag = idx >> 9;
    int ng = frag & 15;
    int tc = frag >> 4;
    int cc = tc % 3, tap = tc / 3;
    int n = ng*16 + (lane & 15);
    int g = n >> 6, o = n & 63;
    int c = cc*32 + ((lane >> 4) << 3) + j;
    int ky = tap / 3, kx = tap % 3;
    float v = 0.0f;
    if (c < CTOT_){
        if (g == 0)      v = Wf[((o*CTOT_ + c)*3 + ky)*3 + kx];
        else if (g == 1) v = Wi[((o*CTOT_ + c)*3 + ky)*3 + kx];
        else if (g == 2) v = Wc[((o*CTOT_ + c)*3 + ky)*3 + kx];
        else             v = (tap == 4) ? Wo[o*CTOT_ + c] : 0.0f;
    } else if (c == CTOT_ && tap == 4){              // bias channel
        v = (g==0) ? bf[o] : (g==1) ? bi[o] : (g==2) ? bc[o] : bo[o];
    }
    Wfrag[idx] = f2bf(v);
}

// x[b][t][c][y][px] fp32 -> xbf[b][t][y][px][c16] bf16 (vector-stageable)
__global__ void prep_xbf(const float* __restrict__ x, unsigned short* __restrict__ xbf){
    int idx = blockIdx.x*256 + threadIdx.x;          // 524288 = (b,t,y,px) flat
    int px = idx & 63;
    int y  = (idx >> 6) & 63;
    int bt = idx >> 12;
    const float* src = x + (size_t)bt*CIN_*HW_ + y*W_ + px;
    unsigned short tmp[16];
    #pragma unroll
    for (int c = 0; c < 16; ++c) tmp[c] = f2bf(src[(size_t)c*HW_]);
    uint4* dst = (uint4*)(xbf + (size_t)idx*16);
    dst[0] = *(uint4*)(tmp);
    dst[1] = *(uint4*)(tmp + 8);
}

__global__ __launch_bounds__(256, 2) void lstm_step(
    const unsigned short* __restrict__ xbf,
    const unsigned short* __restrict__ Wfrag,
    float* __restrict__ cbuf,                        // [b][y][px][o] fp32, in place
    const unsigned short* __restrict__ hin,          // [b][y][px][o] bf16
    unsigned short* __restrict__ hout,
    float* __restrict__ out,                         // [h|c] std layout, t==15 only
    int t)
{
    __shared__ __align__(16) unsigned short Xs[XS_SIZE];
    const int id   = blockIdx.x;
    // XCD swizzle: id&7 -> XCD; each XCD owns a contiguous 8-row y band so
    // y+-1 halo reads stay XCD-local. 512 blocks = 64/XCD = 2/CU (8 waves/CU).
    const int xcd  = id & 7;
    const int j    = id >> 3;                        // 0..63
    const int y    = xcd*8 + (j & 7);
    const int b    = j >> 3;
    const int tid  = threadIdx.x;
    const int lane = tid & 63;
    const int wn   = tid >> 6;                       // 0..3: N-slice (o 16-group)
    const int l15  = lane & 15;
    const int q    = lane >> 4;

    // ---- T14: issue all global loads FIRST; zero-init runs under their latency
    // x: 3 rows x 64 px x 2 ch8 = 384 uint4 (<=2/thread)
    uint4 xv[2]; bool xok[2] = {false,false};
    int xrow[2], xpx[2], xch8[2];
    #pragma unroll
    for (int k = 0; k < 2; ++k){
        int i = tid + (k << 8);
        if (i < 384){
            xrow[k] = i >> 7; int rem = i & 127; xpx[k] = rem >> 1; xch8[k] = rem & 1;
            int yy = y + xrow[k] - 1;
            if (yy >= 0 && yy < H_){
                xok[k] = true;
                xv[k] = *(const uint4*)(xbf + ((((size_t)(b*T_ + t)*H_ + yy)*W_ + xpx[k])*16 + xch8[k]*8));
            }
        }
    }
    // h: 3 rows x 64 px x 8 ch8 = 1536 uint4 (6/thread)
    uint4 hv[6]; bool hok[6] = {false,false,false,false,false,false};
    int hrow[6], hpx[6], hch8[6];
    if (t > 0){
        #pragma unroll
        for (int k = 0; k < 6; ++k){
            int i = tid + (k << 8);
            hrow[k] = i >> 9; int rem = i & 511; hpx[k] = rem >> 3; hch8[k] = rem & 7;
            int yy = y + hrow[k] - 1;
            if (yy >= 0 && yy < H_){
                hok[k] = true;
                hv[k] = *(const uint4*)(hin + ((((size_t)b*H_ + yy)*W_ + hpx[k])*HID_ + hch8[k]*8));
            }
        }
    }
    // epilogue c prefetch: 8 scalar loads per lane, consumed after K-loop
    const int o = wn*16 + l15;
    float cpv[8];
    if (t > 0){
        #pragma unroll
        for (int mf = 0; mf < 2; ++mf)
            #pragma unroll
            for (int r = 0; r < 4; ++r){
                const int pxo = (mf*2+ (q>>1))*16 + 0; // placeholder to keep shape
                (void)pxo;
            }
        #pragma unroll
        for (int u = 0; u < 8; ++u){
            const int mf = u >> 2, r = u & 3;
            const int pxo = mf*16 + q*4 + r;         // matches epilogue mf in 0..1? no: 4 Mfrags
            (void)pxo;
        }
    }
    // (real prefetch below once Mfrag layout fixed: 4 Mfrags x ... see epilogue)
    float cp[4][4];
    if (t > 0){
        #pragma unroll
        for (int mf = 0; mf < 4; ++mf)
            #pragma unroll
            for (int r = 0; r < 4; ++r){
                const int pxo = mf*16 + q*4 + r;
                cp[mf][r] = cbuf[(((size_t)(b*H_ + y)*W_ + pxo)*HID_ + o)];
            }
    }

    // ---- targeted zero/init (disjoint from staged region: ch<80, px1..64, rows in-bounds)
    uint4 z4; z4.x=z4.y=z4.z=z4.w=0u;
    // P1: per (row,px) position: zero ch80..95 then bias 1.0 at ch80 (same thread, ordered)
    if (tid < 3*XS_ROW){
        unsigned short* p = Xs + (size_t)tid*XS_CH;
        *(uint4*)(p + 80) = z4;
        *(uint4*)(p + 88) = z4;
        p[CTOT_] = 0x3F80;                           // bf16 1.0
    }
    // P2: halo cols px 0 and 65, ch0..79: 6 positions x 10 uint4
    if (tid < 60){
        int pp = tid/10, chunk = tid - pp*10;
        int row = pp >> 1, px = (pp & 1) ? 65 : 0;
        *(uint4*)(Xs + (size_t)(row*XS_ROW + px)*XS_CH + chunk*8) = z4;
    }
    // P3: OOB rows (y edges): zero px1..64, ch0..79
    if (y == 0 || y == H_-1){
        int row = (y == 0) ? 0 : 2;
        for (int i = tid; i < 640; i += 256){
            int px = 1 + i/10, chunk = i - (i/10)*10;
            *(uint4*)(Xs + (size_t)(row*XS_ROW + px)*XS_CH + chunk*8) = z4;
        }
    }
    // P4: t==0: h region zero (rows with yy in-bounds, px1..64, ch16..79)
    if (t == 0){
        for (int i = tid; i < 1536; i += 256){
            int row = i >> 9; int rem = i & 511;
            int px = 1 + (rem >> 3), chunk = rem & 7;
            *(uint4*)(Xs + (size_t)(row*XS_ROW + px)*XS_CH + CIN_ + chunk*8) = z4;
        }
    }

    // ---- commit staged data to LDS (disjoint from zero passes -> no extra barrier)
    #pragma unroll
    for (int k = 0; k < 2; ++k)
        if (xok[k])
            *(uint4*)(Xs + (size_t)(xrow[k]*XS_ROW + xpx[k] + 1)*XS_CH + xch8[k]*8) = xv[k];
    if (t > 0){
        #pragma unroll
        for (int k = 0; k < 6; ++k)
            if (hok[k])
                *(uint4*)(Xs + (size_t)(hrow[k]*XS_ROW + hpx[k] + 1)*XS_CH + CIN_ + hch8[k]*8) = hv[k];
    }
    __syncthreads();

    // ---- K-loop: 27 (cc,tap) iters, one-ahead pipelined; g=3 center tap only.
    // Per wave: M=64 (4 Mfrags) x N=16/gate. 3 B-loads feed 12 MFMAs.
    f32x4 acc[4][4];
    #pragma unroll
    for (int g = 0; g < 4; ++g){
        #pragma unroll
        for (int mf = 0; mf < 4; ++mf) acc[g][mf] = (f32x4)0.0f;
    }

    short8 aC[4], bC[3], bO;
    {   // preload (cc=0, tap=0): ky=0, kx=0
        const unsigned short* ap = Xs + (size_t)l15*XS_CH + q*8;
        #pragma unroll
        for (int mf = 0; mf < 4; ++mf) aC[mf] = *(const short8*)(ap + mf*16*XS_CH);
        const unsigned short* bp = Wfrag + (size_t)wn*512 + lane*8;
        #pragma unroll
        for (int g = 0; g < 3; ++g) bC[g] = *(const short8*)(bp + ((size_t)g << 11));
    }
    for (int cc = 0; cc < 3; ++cc){
        #pragma unroll 1
        for (int tap = 0; tap < 9; ++tap){
            int ncc = cc, ntap = tap + 1;
            if (ntap == 9){ ntap = 0; ++ncc; }
            const bool have = (ncc < 3);
            short8 aN[4], bN[3];
            if (have){
                const int nky = ntap/3, nkx = ntap - 3*(ntap/3);
                const unsigned short* ap =
                    Xs + (size_t)(nky*XS_ROW + l15 + nkx)*XS_CH + ncc*32 + q*8;
                #pragma unroll
                for (int mf = 0; mf < 4; ++mf) aN[mf] = *(const short8*)(ap + mf*16*XS_CH);
                const unsigned short* bp =
                    Wfrag + ((size_t)((ntap*3 + ncc)*16 + wn) << 9) + lane*8;
                #pragma unroll
                for (int g = 0; g < 3; ++g) bN[g] = *(const short8*)(bp + ((size_t)g << 11));
            }
            if (tap == 3)   // prefetch o-gate frag for tap 4
                bO = *(const short8*)(Wfrag + ((size_t)((4*3 + cc)*16 + 12 + wn) << 9) + lane*8);
            if (tap == 4){  // o-gate: center tap only (covers bias ch too)
                #pragma unroll
                for (int mf = 0; mf < 4; ++mf)
                    acc[3][mf] = __builtin_amdgcn_mfma_f32_16x16x32_bf16(aC[mf], bO, acc[3][mf], 0,0,0);
            }
            #pragma unroll
            for (int g = 0; g < 3; ++g){
                #pragma unroll
                for (int mf = 0; mf < 4; ++mf)
                    acc[g][mf] = __builtin_amdgcn_mfma_f32_16x16x32_bf16(aC[mf], bC[g], acc[g][mf], 0,0,0);
            }
            if (have){
                #pragma unroll
                for (int mf = 0; mf < 4; ++mf) aC[mf] = aN[mf];
                bC[0]=bN[0]; bC[1]=bN[1]; bC[2]=bN[2];
            }
        }
    }

    // ---- epilogue: wave-local gates; c in place, channel-last
    #pragma unroll
    for (int mf = 0; mf < 4; ++mf){
        #pragma unroll
        for (int r = 0; r < 4; ++r){
            const int px = mf*16 + q*4 + r;
            const float fv = sigm_(acc[0][mf][r]);
            const float iv = sigm_(acc[1][mf][r]);
            const float gv = tanh_(acc[2][mf][r]);
            const float ov = sigm_(acc[3][mf][r]);
            const size_t cidx = (((size_t)(b*H_ + y)*W_ + px)*HID_ + o);
            const float cprev = t ? cp[mf][r] : 0.0f;
            const float cn = cprev*fv + iv*gv;
            const float hn = tanh_(cn)*ov;
            if (t < T_-1){
                cbuf[cidx] = cn;
                hout[cidx] = f2bf(hn);
            } else {
                const size_t oidx = ((((size_t)(b*HID_ + o))*H_ + y)*W_ + px);
                out[oidx] = hn;
                out[CSTRIDE_ + oidx] = cn;
            }
        }
    }
}

extern "C" void kernel_launch(void* const* d_in, const int* in_sizes, int n_in,
                              void* d_out, int out_size, void* d_ws, size_t ws_size,
                              hipStream_t stream){
    const float* x  = (const float*)d_in[0];
    const float* Wf = (const float*)d_in[1];
    const float* bf = (const float*)d_in[2];
    const float* Wi = (const float*)d_in[3];
    const float* bi = (const float*)d_in[4];
    const float* Wc = (const float*)d_in[5];
    const float* bc = (const float*)d_in[6];
    const float* Wo = (const float*)d_in[7];
    const float* bo = (const float*)d_in[8];

    // ws: Wfrag 442368 | xbf 16777216 | cbuf 8388608 | hbfA 4194304 | hbfB 4194304
    unsigned short* Wfrag = (unsigned short*)d_ws;
    unsigned short* xbf   = (unsigned short*)((char*)d_ws + 442368);
    float*          cbuf  = (float*)((char*)d_ws + 442368 + 16777216);
    unsigned short* hbfA  = (unsigned short*)((char*)d_ws + 442368 + 16777216 + 8388608);
    unsigned short* hbfB  = hbfA + CSTRIDE_;

    prep_wfrag<<<dim3(864), dim3(256), 0, stream>>>(Wf, Wi, Wc, Wo, bf, bi, bc, bo, Wfrag);
    prep_xbf<<<dim3(2048), dim3(256), 0, stream>>>(x, xbf);

    for (int t = 0; t < T_; ++t){
        const unsigned short* hi = (t & 1) ? hbfA : hbfB;   // t==0 never reads
        unsigned short*       ho = (t & 1) ? hbfB : hbfA;
        lstm_step<<<dim3(512), dim3(256), 0, stream>>>(
            xbf, Wfrag, cbuf, hi, ho, (float*)d_out, t);
    }
}

// Round 4
// 440.329 us; speedup vs baseline: 1.5074x; 1.5074x over previous
//
#include <hip/hip_runtime.h>

// ConvLSTM B=8,T=16,CIN=16,HID=64,H=W=64,K=3 'SAME' — 16-launch bf16 MFMA.
// Round-7: REVERT to round-4 structure (256 blocks x 512 thr, M=128 = 2 rows,
// 8 waves = 2Mrow x 4Nslice, M_wave=64). Round-6's 512-block variant doubled
// the per-XCD Wfrag L2 stream (10.4 -> 20.7 MB/step) and thrashed the
// L2-resident cbuf/hbf state: FETCH 2->15MB, WRITE 12->29MB. Budget rule:
// keep blocks/XCD x 324KB within L2 reuse tolerance (32 blocks/XCD OK).
// Traffic-neutral deltas vs round-4:
//  (1) #pragma unroll 3 on tap loop (kills ~28 v_mov/iter reg copies),
//  (2) targeted LDS init (only ch80..95 + halo cols + OOB rows + t0 h-region;
//      ~600 vs 3432 uint4, one barrier removed),
//  (3) T14 early-issue staging loads (latency hides under init VALU).

#define B_ 8
#define T_ 16
#define CIN_ 16
#define HID_ 64
#define H_ 64
#define W_ 64
#define HW_ (H_*W_)
#define CTOT_ 80
#define XS_ROW 66                  // 64 px + 2 halo
#define XS_CH 104                  // 96 K-channels + 8 pad
#define XS_SIZE (4*XS_ROW*XS_CH)   // 27456 hw = 54912 B
#define CSTRIDE_ (B_*HID_*HW_)     // 2097152

typedef __attribute__((ext_vector_type(8))) short short8;
typedef __attribute__((ext_vector_type(4))) float f32x4;

__device__ __forceinline__ unsigned short f2bf(float f){
    unsigned u = __float_as_uint(f);
    u = (u + 0x7FFFu + ((u >> 16) & 1u)) >> 16;   // RNE
    return (unsigned short)u;
}
__device__ __forceinline__ float sigm_(float v){ return 1.0f/(1.0f + __expf(-v)); }
__device__ __forceinline__ float tanh_(float v){ return 2.0f/(1.0f + __expf(-2.0f*v)) - 1.0f; }

// Wfrag: [tap 9][cc 3][ng 16] frags of 512 hw ([lane][j]).
// n = ng*16+(lane&15): g=n>>6, o=n&63; k-ch c = cc*32+(lane>>4)*8+j.
// Bias folded at c==80 (constant-1 A channel), center tap only.
__global__ void prep_wfrag(const float* __restrict__ Wf, const float* __restrict__ Wi,
                           const float* __restrict__ Wc, const float* __restrict__ Wo,
                           const float* __restrict__ bf, const float* __restrict__ bi,
                           const float* __restrict__ bc, const float* __restrict__ bo,
                           unsigned short* __restrict__ Wfrag){
    int idx = blockIdx.x*256 + threadIdx.x;          // 864*256 = 221184 exact
    int j    = idx & 7;
    int lane = (idx >> 3) & 63;
    int frag = idx >> 9;
    int ng = frag & 15;
    int tc = frag >> 4;
    int cc = tc % 3, tap = tc / 3;
    int n = ng*16 + (lane & 15);
    int g = n >> 6, o = n & 63;
    int c = cc*32 + ((lane >> 4) << 3) + j;
    int ky = tap / 3, kx = tap % 3;
    float v = 0.0f;
    if (c < CTOT_){
        if (g == 0)      v = Wf[((o*CTOT_ + c)*3 + ky)*3 + kx];
        else if (g == 1) v = Wi[((o*CTOT_ + c)*3 + ky)*3 + kx];
        else if (g == 2) v = Wc[((o*CTOT_ + c)*3 + ky)*3 + kx];
        else             v = (tap == 4) ? Wo[o*CTOT_ + c] : 0.0f;
    } else if (c == CTOT_ && tap == 4){              // bias channel
        v = (g==0) ? bf[o] : (g==1) ? bi[o] : (g==2) ? bc[o] : bo[o];
    }
    Wfrag[idx] = f2bf(v);
}

// x[b][t][c][y][px] fp32 -> xbf[b][t][y][px][c16] bf16 (vector-stageable)
__global__ void prep_xbf(const float* __restrict__ x, unsigned short* __restrict__ xbf){
    int idx = blockIdx.x*256 + threadIdx.x;          // 524288 = (b,t,y,px) flat
    int px = idx & 63;
    int y  = (idx >> 6) & 63;
    int bt = idx >> 12;
    const float* src = x + (size_t)bt*CIN_*HW_ + y*W_ + px;
    unsigned short tmp[16];
    #pragma unroll
    for (int c = 0; c < 16; ++c) tmp[c] = f2bf(src[(size_t)c*HW_]);
    uint4* dst = (uint4*)(xbf + (size_t)idx*16);
    dst[0] = *(uint4*)(tmp);
    dst[1] = *(uint4*)(tmp + 8);
}

__global__ __launch_bounds__(512, 2) void lstm_step(
    const unsigned short* __restrict__ xbf,
    const unsigned short* __restrict__ Wfrag,
    float* __restrict__ cbuf,                        // [b][y][px][o] fp32, in place
    const unsigned short* __restrict__ hin,          // [b][y][px][o] bf16
    unsigned short* __restrict__ hout,
    float* __restrict__ out,                         // [h|c] std layout, t==15 only
    int t)
{
    __shared__ __align__(16) unsigned short Xs[XS_SIZE];
    const int id   = blockIdx.x;
    // XCD swizzle: id&7 -> XCD; each XCD owns a contiguous 8-row y band so
    // y+-1 halo reads stay XCD-local. 256 blocks = 32/XCD = 1/CU.
    const int xcd  = id & 7;
    const int j    = id >> 3;
    const int b    = j >> 2;
    const int y0   = xcd*8 + ((j & 3) << 1);         // row-pair start
    const int tid  = threadIdx.x;
    const int lane = tid & 63;
    const int wid  = tid >> 6;
    const int wm   = wid >> 2;                       // 0/1: which output row
    const int wn   = wid & 3;                        // N-slice
    const int l15  = lane & 15;
    const int q    = lane >> 4;

    // ---- T14: issue staging global loads FIRST (latency hides under init)
    // x: 4 rows x 64 px x 2 ch8 = 512 uint4 (exactly 1/thread)
    uint4 xv; bool xok = false;
    int xrow = tid >> 7, xpx, xch8;
    {
        int rem = tid & 127; xpx = rem >> 1; xch8 = rem & 1;
        int yy = y0 + xrow - 1;
        if (yy >= 0 && yy < H_){
            xok = true;
            xv = *(const uint4*)(xbf + ((((size_t)(b*T_ + t)*H_ + yy)*W_ + xpx)*16 + xch8*8));
        }
    }
    // h: 4 rows x 64 px x 8 ch8 = 2048 uint4 (4/thread)
    uint4 hv[4]; bool hok[4] = {false,false,false,false};
    int hrow[4], hpx[4], hch8[4];
    if (t > 0){
        #pragma unroll
        for (int k = 0; k < 4; ++k){
            int i = tid + (k << 9);
            hrow[k] = i >> 9; int rem = i & 511; hpx[k] = rem >> 3; hch8[k] = rem & 7;
            int yy = y0 + hrow[k] - 1;
            if (yy >= 0 && yy < H_){
                hok[k] = true;
                hv[k] = *(const uint4*)(hin + ((((size_t)b*H_ + yy)*W_ + hpx[k])*HID_ + hch8[k]*8));
            }
        }
    }

    // ---- targeted init (regions disjoint from staged commits -> one barrier)
    uint4 z4; z4.x=z4.y=z4.z=z4.w=0u;
    // P1: every (row,px): zero ch80..95, then bias 1.0 at ch80 (same thread)
    if (tid < 4*XS_ROW){
        unsigned short* p = Xs + (size_t)tid*XS_CH;
        *(uint4*)(p + 80) = z4;
        *(uint4*)(p + 88) = z4;
        p[CTOT_] = 0x3F80;                           // bf16 1.0
    }
    // P2: halo cols px0 & px65, ch0..79: 8 positions x 10 uint4 = 80
    if (tid < 80){
        int pp = tid/10, chunk = tid - pp*10;
        int row = pp >> 1, px = (pp & 1) ? 65 : 0;
        *(uint4*)(Xs + (size_t)(row*XS_ROW + px)*XS_CH + chunk*8) = z4;
    }
    // P3: OOB edge rows (y0==0 -> row0, y0==62 -> row3): px1..64, ch0..79
    if (y0 == 0 || y0 == H_-2){
        int row = (y0 == 0) ? 0 : 3;
        for (int i = tid; i < 640; i += 512){
            int px = 1 + i/10, chunk = i - (i/10)*10;
            *(uint4*)(Xs + (size_t)(row*XS_ROW + px)*XS_CH + chunk*8) = z4;
        }
    }
    // P4: t==0: h region zero, rows 0..3, px1..64, ch16..79 (4/thread)
    if (t == 0){
        #pragma unroll
        for (int k = 0; k < 4; ++k){
            int i = tid + (k << 9);
            int row = i >> 9; int rem = i & 511;
            int px = 1 + (rem >> 3), chunk = rem & 7;
            *(uint4*)(Xs + (size_t)(row*XS_ROW + px)*XS_CH + CIN_ + chunk*8) = z4;
        }
    }

    // ---- commit staged data (addresses disjoint from P1..P4)
    if (xok)
        *(uint4*)(Xs + (size_t)(xrow*XS_ROW + xpx + 1)*XS_CH + xch8*8) = xv;
    if (t > 0){
        #pragma unroll
        for (int k = 0; k < 4; ++k)
            if (hok[k])
                *(uint4*)(Xs + (size_t)(hrow[k]*XS_ROW + hpx[k] + 1)*XS_CH + CIN_ + hch8[k]*8) = hv[k];
    }
    __syncthreads();

    // ---- K-loop: 27 (cc,tap) iters, one-ahead pipelined; g=3 center tap only.
    // Per wave: M=64 (4 Mfrags) x N=16/gate. 3 B-loads feed 12 MFMAs.
    f32x4 acc[4][4];
    #pragma unroll
    for (int g = 0; g < 4; ++g){
        #pragma unroll
        for (int mf = 0; mf < 4; ++mf) acc[g][mf] = (f32x4)0.0f;
    }

    short8 aC[4], bC[3], bO;
    {   // preload (cc=0, tap=0): ky=0, kx=0
        const unsigned short* ap = Xs + (size_t)(wm*XS_ROW + l15)*XS_CH + q*8;
        #pragma unroll
        for (int mf = 0; mf < 4; ++mf) aC[mf] = *(const short8*)(ap + mf*16*XS_CH);
        const unsigned short* bp = Wfrag + (size_t)wn*512 + lane*8;
        #pragma unroll
        for (int g = 0; g < 3; ++g) bC[g] = *(const short8*)(bp + ((size_t)g << 11));
    }
    for (int cc = 0; cc < 3; ++cc){
        #pragma unroll 3
        for (int tap = 0; tap < 9; ++tap){
            int ncc = cc, ntap = tap + 1;
            if (ntap == 9){ ntap = 0; ++ncc; }
            const bool have = (ncc < 3);
            short8 aN[4], bN[3];
            if (have){
                const int nky = ntap/3, nkx = ntap - 3*(ntap/3);
                const unsigned short* ap =
                    Xs + (size_t)((wm + nky)*XS_ROW + l15 + nkx)*XS_CH + ncc*32 + q*8;
                #pragma unroll
                for (int mf = 0; mf < 4; ++mf) aN[mf] = *(const short8*)(ap + mf*16*XS_CH);
                const unsigned short* bp =
                    Wfrag + ((size_t)((ntap*3 + ncc)*16 + wn) << 9) + lane*8;
                #pragma unroll
                for (int g = 0; g < 3; ++g) bN[g] = *(const short8*)(bp + ((size_t)g << 11));
            }
            if (tap == 1)   // prefetch o-gate frag (used at tap 4: ~3 taps of slack)
                bO = *(const short8*)(Wfrag + ((size_t)((4*3 + cc)*16 + 12 + wn) << 9) + lane*8);
            if (tap == 4){  // o-gate: center tap only (covers bias ch too)
                #pragma unroll
                for (int mf = 0; mf < 4; ++mf)
                    acc[3][mf] = __builtin_amdgcn_mfma_f32_16x16x32_bf16(aC[mf], bO, acc[3][mf], 0,0,0);
            }
            #pragma unroll
            for (int g = 0; g < 3; ++g){
                #pragma unroll
                for (int mf = 0; mf < 4; ++mf)
                    acc[g][mf] = __builtin_amdgcn_mfma_f32_16x16x32_bf16(aC[mf], bC[g], acc[g][mf], 0,0,0);
            }
            if (have){
                #pragma unroll
                for (int mf = 0; mf < 4; ++mf) aC[mf] = aN[mf];
                bC[0]=bN[0]; bC[1]=bN[1]; bC[2]=bN[2];
            }
        }
    }

    // ---- epilogue: wave-local gates; c in place, channel-last
    const int o = wn*16 + l15;
    const int y = y0 + wm;
    #pragma unroll
    for (int mf = 0; mf < 4; ++mf){
        #pragma unroll
        for (int r = 0; r < 4; ++r){
            const int px = mf*16 + q*4 + r;
            const float fv = sigm_(acc[0][mf][r]);
            const float iv = sigm_(acc[1][mf][r]);
            const float gv = tanh_(acc[2][mf][r]);
            const float ov = sigm_(acc[3][mf][r]);
            const size_t cidx = (((size_t)(b*H_ + y)*W_ + px)*HID_ + o);
            const float cprev = t ? cbuf[cidx] : 0.0f;
            const float cn = cprev*fv + iv*gv;
            const float hn = tanh_(cn)*ov;
            if (t < T_-1){
                cbuf[cidx] = cn;
                hout[cidx] = f2bf(hn);
            } else {
                const size_t oidx = ((((size_t)(b*HID_ + o))*H_ + y)*W_ + px);
                out[oidx] = hn;
                out[CSTRIDE_ + oidx] = cn;
            }
        }
    }
}

extern "C" void kernel_launch(void* const* d_in, const int* in_sizes, int n_in,
                              void* d_out, int out_size, void* d_ws, size_t ws_size,
                              hipStream_t stream){
    const float* x  = (const float*)d_in[0];
    const float* Wf = (const float*)d_in[1];
    const float* bf = (const float*)d_in[2];
    const float* Wi = (const float*)d_in[3];
    const float* bi = (const float*)d_in[4];
    const float* Wc = (const float*)d_in[5];
    const float* bc = (const float*)d_in[6];
    const float* Wo = (const float*)d_in[7];
    const float* bo = (const float*)d_in[8];

    // ws: Wfrag 442368 | xbf 16777216 | cbuf 8388608 | hbfA 4194304 | hbfB 4194304
    unsigned short* Wfrag = (unsigned short*)d_ws;
    unsigned short* xbf   = (unsigned short*)((char*)d_ws + 442368);
    float*          cbuf  = (float*)((char*)d_ws + 442368 + 16777216);
    unsigned short* hbfA  = (unsigned short*)((char*)d_ws + 442368 + 16777216 + 8388608);
    unsigned short* hbfB  = hbfA + CSTRIDE_;

    prep_wfrag<<<dim3(864), dim3(256), 0, stream>>>(Wf, Wi, Wc, Wo, bf, bi, bc, bo, Wfrag);
    prep_xbf<<<dim3(2048), dim3(256), 0, stream>>>(x, xbf);

    for (int t = 0; t < T_; ++t){
        const unsigned short* hi = (t & 1) ? hbfA : hbfB;   // t==0 never reads
        unsigned short*       ho = (t & 1) ? hbfB : hbfA;
        lstm_step<<<dim3(256), dim3(512), 0, stream>>>(
            xbf, Wfrag, cbuf, hi, ho, (float*)d_out, t);
    }
}

// Round 5
// 404.355 us; speedup vs baseline: 1.6415x; 1.0890x over previous
//
#include <hip/hip_runtime.h>

// ConvLSTM B=8,T=16,CIN=16,HID=64,H=W=64,K=3 'SAME' — 16-launch bf16 MFMA.
// Round-8: round-4 structure (256 blk x 512 thr, M=128, 8 waves = 2Mrow x
// 4Nslice, M_wave=64; staging/epilogue verbatim from the 420us round-4) with
// ONE change: the K-loop is flipped tap-major (tc = tap*3+cc linear, matches
// Wfrag layout) and FULLY unrolled. All A-fragment LDS addresses become
// Abase + compile-time constants (<38KB -> ds_read_b128 offset: immediates,
// zero per-iter VALU); B advances by constant strides the compiler strength-
// reduces; aC/aN rotation copies become SSA renames. Attacks round-4's
// VALUBusy(19.5%) = 2.3 x MfmaUtil(8.6%) imbalance and shortens the serial
// addr->load->mfma chain that 2 waves/SIMD cannot hide.

#define B_ 8
#define T_ 16
#define CIN_ 16
#define HID_ 64
#define H_ 64
#define W_ 64
#define HW_ (H_*W_)
#define CTOT_ 80
#define XS_ROW 66                  // 64 px + 2 halo
#define XS_CH 104                  // 96 K-channels + 8 pad
#define XS_SIZE (4*XS_ROW*XS_CH)   // 27456 hw = 54912 B
#define CSTRIDE_ (B_*HID_*HW_)     // 2097152

typedef __attribute__((ext_vector_type(8))) short short8;
typedef __attribute__((ext_vector_type(4))) float f32x4;

__device__ __forceinline__ unsigned short f2bf(float f){
    unsigned u = __float_as_uint(f);
    u = (u + 0x7FFFu + ((u >> 16) & 1u)) >> 16;   // RNE
    return (unsigned short)u;
}
__device__ __forceinline__ float sigm_(float v){ return 1.0f/(1.0f + __expf(-v)); }
__device__ __forceinline__ float tanh_(float v){ return 2.0f/(1.0f + __expf(-2.0f*v)) - 1.0f; }

// Wfrag: [tap 9][cc 3][ng 16] frags of 512 hw ([lane][j]).
// n = ng*16+(lane&15): g=n>>6, o=n&63; k-ch c = cc*32+(lane>>4)*8+j.
// Bias folded at c==80 (constant-1 A channel), center tap only.
__global__ void prep_wfrag(const float* __restrict__ Wf, const float* __restrict__ Wi,
                           const float* __restrict__ Wc, const float* __restrict__ Wo,
                           const float* __restrict__ bf, const float* __restrict__ bi,
                           const float* __restrict__ bc, const float* __restrict__ bo,
                           unsigned short* __restrict__ Wfrag){
    int idx = blockIdx.x*256 + threadIdx.x;          // 864*256 = 221184 exact
    int j    = idx & 7;
    int lane = (idx >> 3) & 63;
    int frag = idx >> 9;
    int ng = frag & 15;
    int tc = frag >> 4;
    int cc = tc % 3, tap = tc / 3;
    int n = ng*16 + (lane & 15);
    int g = n >> 6, o = n & 63;
    int c = cc*32 + ((lane >> 4) << 3) + j;
    int ky = tap / 3, kx = tap % 3;
    float v = 0.0f;
    if (c < CTOT_){
        if (g == 0)      v = Wf[((o*CTOT_ + c)*3 + ky)*3 + kx];
        else if (g == 1) v = Wi[((o*CTOT_ + c)*3 + ky)*3 + kx];
        else if (g == 2) v = Wc[((o*CTOT_ + c)*3 + ky)*3 + kx];
        else             v = (tap == 4) ? Wo[o*CTOT_ + c] : 0.0f;
    } else if (c == CTOT_ && tap == 4){              // bias channel
        v = (g==0) ? bf[o] : (g==1) ? bi[o] : (g==2) ? bc[o] : bo[o];
    }
    Wfrag[idx] = f2bf(v);
}

// x[b][t][c][y][px] fp32 -> xbf[b][t][y][px][c16] bf16 (vector-stageable)
__global__ void prep_xbf(const float* __restrict__ x, unsigned short* __restrict__ xbf){
    int idx = blockIdx.x*256 + threadIdx.x;          // 524288 = (b,t,y,px) flat
    int px = idx & 63;
    int y  = (idx >> 6) & 63;
    int bt = idx >> 12;
    const float* src = x + (size_t)bt*CIN_*HW_ + y*W_ + px;
    unsigned short tmp[16];
    #pragma unroll
    for (int c = 0; c < 16; ++c) tmp[c] = f2bf(src[(size_t)c*HW_]);
    uint4* dst = (uint4*)(xbf + (size_t)idx*16);
    dst[0] = *(uint4*)(tmp);
    dst[1] = *(uint4*)(tmp + 8);
}

__global__ __launch_bounds__(512, 2) void lstm_step(
    const unsigned short* __restrict__ xbf,
    const unsigned short* __restrict__ Wfrag,
    float* __restrict__ cbuf,                        // [b][y][px][o] fp32, in place
    const unsigned short* __restrict__ hin,          // [b][y][px][o] bf16
    unsigned short* __restrict__ hout,
    float* __restrict__ out,                         // [h|c] std layout, t==15 only
    int t)
{
    __shared__ __align__(16) unsigned short Xs[XS_SIZE];
    const int id   = blockIdx.x;
    // XCD swizzle: id&7 -> XCD; each XCD owns a contiguous 8-row y band so
    // y+-1 halo reads stay XCD-local. 256 blocks = 32/XCD = 1/CU.
    const int xcd  = id & 7;
    const int j    = id >> 3;
    const int b    = j >> 2;
    const int y0   = xcd*8 + ((j & 3) << 1);         // row-pair start
    const int tid  = threadIdx.x;
    const int lane = tid & 63;
    const int wid  = tid >> 6;
    const int wm   = wid >> 2;                       // 0/1: which output row
    const int wn   = wid & 3;                        // N-slice
    const int l15  = lane & 15;
    const int q    = lane >> 4;

    // ---- zero LDS (SAME-pad borders + OOB rows + pad channels)
    uint4 z4; z4.x=z4.y=z4.z=z4.w=0u;
    for (int i = tid; i < XS_SIZE/8; i += 512) ((uint4*)Xs)[i] = z4;
    __syncthreads();

    // ---- stage x: 4 rows x 64 px x 2 ch-chunks = 512 uint4 (exactly 1/thread)
    {
        int row = tid >> 7, rem = tid & 127;
        int px = rem >> 1, ch8 = rem & 1;
        int yy = y0 + row - 1;
        if (yy >= 0 && yy < H_){
            uint4 v = *(const uint4*)(xbf + ((((size_t)(b*T_ + t)*H_ + yy)*W_ + px)*16 + ch8*8));
            *(uint4*)(Xs + ((size_t)(row*XS_ROW + px + 1))*XS_CH + ch8*8) = v;
        }
    }
    // ---- stage h: 4 rows x 64 px x 8 ch-chunks = 2048 uint4 (4/thread)
    if (t > 0){
        #pragma unroll
        for (int k = 0; k < 4; ++k){
            int i = tid + (k << 9);
            int row = i >> 9, rem = i & 511;
            int px = rem >> 3, ch8 = rem & 7;
            int yy = y0 + row - 1;
            if (yy >= 0 && yy < H_){
                uint4 v = *(const uint4*)(hin + ((((size_t)b*H_ + yy)*W_ + px)*HID_ + ch8*8));
                *(uint4*)(Xs + (size_t)(row*XS_ROW + px + 1)*XS_CH + CIN_ + ch8*8) = v;
            }
        }
    }
    // ---- constant-1 bias channel (ch 80); OOB positions only feed zero weights
    for (int i = tid; i < 4*XS_ROW; i += 512)
        Xs[i*XS_CH + CTOT_] = 0x3F80;                // bf16 1.0
    __syncthreads();

    // ---- K-loop: 27 tc = tap*3+cc iters, FULLY unrolled, tap-major (linear
    // in Wfrag). A addresses = Abase + constant (ds_read offset: imm, 0 VALU);
    // B addresses = Bbase + tc*8192 + g*2048 elements (scalar-strength-reduced).
    // One-ahead rotation kept; copies become SSA renames under full unroll.
    f32x4 acc[4][4];
    #pragma unroll
    for (int g = 0; g < 4; ++g){
        #pragma unroll
        for (int mf = 0; mf < 4; ++mf) acc[g][mf] = (f32x4)0.0f;
    }

    const unsigned short* Abase = Xs + (size_t)(wm*XS_ROW + l15)*XS_CH + q*8;
    const unsigned short* Bbase = Wfrag + (size_t)wn*512 + lane*8;

    short8 aC[4], bC[3];
    #pragma unroll
    for (int mf = 0; mf < 4; ++mf) aC[mf] = *(const short8*)(Abase + mf*16*XS_CH);
    #pragma unroll
    for (int g = 0; g < 3; ++g) bC[g] = *(const short8*)(Bbase + g*2048);

    #pragma unroll
    for (int tc = 0; tc < 27; ++tc){
        const int tap = tc/3;
        short8 aN[4], bN[3];
        if (tc < 26){
            const int ntc = tc + 1;
            const int ntap = ntc/3, ncc = ntc%3;
            const int nky = ntap/3, nkx = ntap%3;
            const int aoff = (nky*XS_ROW + nkx)*XS_CH + ncc*32;  // elements, const
            #pragma unroll
            for (int mf = 0; mf < 4; ++mf)
                aN[mf] = *(const short8*)(Abase + aoff + mf*16*XS_CH);
            #pragma unroll
            for (int g = 0; g < 3; ++g)
                bN[g] = *(const short8*)(Bbase + ntc*8192 + g*2048);
        }
        if (tap == 4){  // o-gate: center tap only (ng=12+wn; covers bias ch)
            const short8 bO = *(const short8*)(Bbase + tc*8192 + 6144);
            #pragma unroll
            for (int mf = 0; mf < 4; ++mf)
                acc[3][mf] = __builtin_amdgcn_mfma_f32_16x16x32_bf16(aC[mf], bO, acc[3][mf], 0,0,0);
        }
        #pragma unroll
        for (int g = 0; g < 3; ++g){
            #pragma unroll
            for (int mf = 0; mf < 4; ++mf)
                acc[g][mf] = __builtin_amdgcn_mfma_f32_16x16x32_bf16(aC[mf], bC[g], acc[g][mf], 0,0,0);
        }
        if (tc < 26){
            #pragma unroll
            for (int mf = 0; mf < 4; ++mf) aC[mf] = aN[mf];
            bC[0]=bN[0]; bC[1]=bN[1]; bC[2]=bN[2];
        }
    }

    // ---- epilogue: wave-local gates; c in place, channel-last
    const int o = wn*16 + l15;
    const int y = y0 + wm;
    #pragma unroll
    for (int mf = 0; mf < 4; ++mf){
        #pragma unroll
        for (int r = 0; r < 4; ++r){
            const int px = mf*16 + q*4 + r;
            const float fv = sigm_(acc[0][mf][r]);
            const float iv = sigm_(acc[1][mf][r]);
            const float gv = tanh_(acc[2][mf][r]);
            const float ov = sigm_(acc[3][mf][r]);
            const size_t cidx = (((size_t)(b*H_ + y)*W_ + px)*HID_ + o);
            const float cprev = t ? cbuf[cidx] : 0.0f;
            const float cn = cprev*fv + iv*gv;
            const float hn = tanh_(cn)*ov;
            if (t < T_-1){
                cbuf[cidx] = cn;
                hout[cidx] = f2bf(hn);
            } else {
                const size_t oidx = ((((size_t)(b*HID_ + o))*H_ + y)*W_ + px);
                out[oidx] = hn;
                out[CSTRIDE_ + oidx] = cn;
            }
        }
    }
}

extern "C" void kernel_launch(void* const* d_in, const int* in_sizes, int n_in,
                              void* d_out, int out_size, void* d_ws, size_t ws_size,
                              hipStream_t stream){
    const float* x  = (const float*)d_in[0];
    const float* Wf = (const float*)d_in[1];
    const float* bf = (const float*)d_in[2];
    const float* Wi = (const float*)d_in[3];
    const float* bi = (const float*)d_in[4];
    const float* Wc = (const float*)d_in[5];
    const float* bc = (const float*)d_in[6];
    const float* Wo = (const float*)d_in[7];
    const float* bo = (const float*)d_in[8];

    // ws: Wfrag 442368 | xbf 16777216 | cbuf 8388608 | hbfA 4194304 | hbfB 4194304
    unsigned short* Wfrag = (unsigned short*)d_ws;
    unsigned short* xbf   = (unsigned short*)((char*)d_ws + 442368);
    float*          cbuf  = (float*)((char*)d_ws + 442368 + 16777216);
    unsigned short* hbfA  = (unsigned short*)((char*)d_ws + 442368 + 16777216 + 8388608);
    unsigned short* hbfB  = hbfA + CSTRIDE_;

    prep_wfrag<<<dim3(864), dim3(256), 0, stream>>>(Wf, Wi, Wc, Wo, bf, bi, bc, bo, Wfrag);
    prep_xbf<<<dim3(2048), dim3(256), 0, stream>>>(x, xbf);

    for (int t = 0; t < T_; ++t){
        const unsigned short* hi = (t & 1) ? hbfA : hbfB;   // t==0 never reads
        unsigned short*       ho = (t & 1) ? hbfB : hbfA;
        lstm_step<<<dim3(256), dim3(512), 0, stream>>>(
            xbf, Wfrag, cbuf, hi, ho, (float*)d_out, t);
    }
}

// Round 6
// 396.920 us; speedup vs baseline: 1.6723x; 1.0187x over previous
//
#include <hip/hip_runtime.h>

// ConvLSTM B=8,T=16,CIN=16,HID=64,H=W=64,K=3 'SAME' — 16-launch bf16 MFMA.
// Round-9: round-8 base (fully-unrolled tap-major K-loop, const LDS offsets,
// 256 blk x 512 thr, M=128) + ONE change: prefetch depth 1 -> 2 for both A
// (ds_read, ~120cy) and B (L2, ~200-300cy). Per-iter MFMA cover is only
// ~80cy x 2 waves/SIMD; one-ahead strands 50-150cy/iter on the B chain.
// Full unroll keeps rotation indices (tc%3) compile-time -> registers, no
// scratch. o-gate frags prefetched 2 iters early (tc=10..12 for 12..14).

#define B_ 8
#define T_ 16
#define CIN_ 16
#define HID_ 64
#define H_ 64
#define W_ 64
#define HW_ (H_*W_)
#define CTOT_ 80
#define XS_ROW 66                  // 64 px + 2 halo
#define XS_CH 104                  // 96 K-channels + 8 pad
#define XS_SIZE (4*XS_ROW*XS_CH)   // 27456 hw = 54912 B
#define CSTRIDE_ (B_*HID_*HW_)     // 2097152

typedef __attribute__((ext_vector_type(8))) short short8;
typedef __attribute__((ext_vector_type(4))) float f32x4;

__device__ __forceinline__ unsigned short f2bf(float f){
    unsigned u = __float_as_uint(f);
    u = (u + 0x7FFFu + ((u >> 16) & 1u)) >> 16;   // RNE
    return (unsigned short)u;
}
__device__ __forceinline__ float sigm_(float v){ return 1.0f/(1.0f + __expf(-v)); }
__device__ __forceinline__ float tanh_(float v){ return 2.0f/(1.0f + __expf(-2.0f*v)) - 1.0f; }

// Wfrag: [tap 9][cc 3][ng 16] frags of 512 hw ([lane][j]).
// n = ng*16+(lane&15): g=n>>6, o=n&63; k-ch c = cc*32+(lane>>4)*8+j.
// Bias folded at c==80 (constant-1 A channel), center tap only.
__global__ void prep_wfrag(const float* __restrict__ Wf, const float* __restrict__ Wi,
                           const float* __restrict__ Wc, const float* __restrict__ Wo,
                           const float* __restrict__ bf, const float* __restrict__ bi,
                           const float* __restrict__ bc, const float* __restrict__ bo,
                           unsigned short* __restrict__ Wfrag){
    int idx = blockIdx.x*256 + threadIdx.x;          // 864*256 = 221184 exact
    int j    = idx & 7;
    int lane = (idx >> 3) & 63;
    int frag = idx >> 9;
    int ng = frag & 15;
    int tc = frag >> 4;
    int cc = tc % 3, tap = tc / 3;
    int n = ng*16 + (lane & 15);
    int g = n >> 6, o = n & 63;
    int c = cc*32 + ((lane >> 4) << 3) + j;
    int ky = tap / 3, kx = tap % 3;
    float v = 0.0f;
    if (c < CTOT_){
        if (g == 0)      v = Wf[((o*CTOT_ + c)*3 + ky)*3 + kx];
        else if (g == 1) v = Wi[((o*CTOT_ + c)*3 + ky)*3 + kx];
        else if (g == 2) v = Wc[((o*CTOT_ + c)*3 + ky)*3 + kx];
        else             v = (tap == 4) ? Wo[o*CTOT_ + c] : 0.0f;
    } else if (c == CTOT_ && tap == 4){              // bias channel
        v = (g==0) ? bf[o] : (g==1) ? bi[o] : (g==2) ? bc[o] : bo[o];
    }
    Wfrag[idx] = f2bf(v);
}

// x[b][t][c][y][px] fp32 -> xbf[b][t][y][px][c16] bf16 (vector-stageable)
__global__ void prep_xbf(const float* __restrict__ x, unsigned short* __restrict__ xbf){
    int idx = blockIdx.x*256 + threadIdx.x;          // 524288 = (b,t,y,px) flat
    int px = idx & 63;
    int y  = (idx >> 6) & 63;
    int bt = idx >> 12;
    const float* src = x + (size_t)bt*CIN_*HW_ + y*W_ + px;
    unsigned short tmp[16];
    #pragma unroll
    for (int c = 0; c < 16; ++c) tmp[c] = f2bf(src[(size_t)c*HW_]);
    uint4* dst = (uint4*)(xbf + (size_t)idx*16);
    dst[0] = *(uint4*)(tmp);
    dst[1] = *(uint4*)(tmp + 8);
}

__global__ __launch_bounds__(512, 2) void lstm_step(
    const unsigned short* __restrict__ xbf,
    const unsigned short* __restrict__ Wfrag,
    float* __restrict__ cbuf,                        // [b][y][px][o] fp32, in place
    const unsigned short* __restrict__ hin,          // [b][y][px][o] bf16
    unsigned short* __restrict__ hout,
    float* __restrict__ out,                         // [h|c] std layout, t==15 only
    int t)
{
    __shared__ __align__(16) unsigned short Xs[XS_SIZE];
    const int id   = blockIdx.x;
    // XCD swizzle: id&7 -> XCD; each XCD owns a contiguous 8-row y band so
    // y+-1 halo reads stay XCD-local. 256 blocks = 32/XCD = 1/CU.
    const int xcd  = id & 7;
    const int j    = id >> 3;
    const int b    = j >> 2;
    const int y0   = xcd*8 + ((j & 3) << 1);         // row-pair start
    const int tid  = threadIdx.x;
    const int lane = tid & 63;
    const int wid  = tid >> 6;
    const int wm   = wid >> 2;                       // 0/1: which output row
    const int wn   = wid & 3;                        // N-slice
    const int l15  = lane & 15;
    const int q    = lane >> 4;

    // ---- zero LDS (SAME-pad borders + OOB rows + pad channels)
    uint4 z4; z4.x=z4.y=z4.z=z4.w=0u;
    for (int i = tid; i < XS_SIZE/8; i += 512) ((uint4*)Xs)[i] = z4;
    __syncthreads();

    // ---- stage x: 4 rows x 64 px x 2 ch-chunks = 512 uint4 (exactly 1/thread)
    {
        int row = tid >> 7, rem = tid & 127;
        int px = rem >> 1, ch8 = rem & 1;
        int yy = y0 + row - 1;
        if (yy >= 0 && yy < H_){
            uint4 v = *(const uint4*)(xbf + ((((size_t)(b*T_ + t)*H_ + yy)*W_ + px)*16 + ch8*8));
            *(uint4*)(Xs + ((size_t)(row*XS_ROW + px + 1))*XS_CH + ch8*8) = v;
        }
    }
    // ---- stage h: 4 rows x 64 px x 8 ch-chunks = 2048 uint4 (4/thread)
    if (t > 0){
        #pragma unroll
        for (int k = 0; k < 4; ++k){
            int i = tid + (k << 9);
            int row = i >> 9, rem = i & 511;
            int px = rem >> 3, ch8 = rem & 7;
            int yy = y0 + row - 1;
            if (yy >= 0 && yy < H_){
                uint4 v = *(const uint4*)(hin + ((((size_t)b*H_ + yy)*W_ + px)*HID_ + ch8*8));
                *(uint4*)(Xs + (size_t)(row*XS_ROW + px + 1)*XS_CH + CIN_ + ch8*8) = v;
            }
        }
    }
    // ---- constant-1 bias channel (ch 80); OOB positions only feed zero weights
    for (int i = tid; i < 4*XS_ROW; i += 512)
        Xs[i*XS_CH + CTOT_] = 0x3F80;                // bf16 1.0
    __syncthreads();

    // ---- K-loop: 27 tc = tap*3+cc iters, FULLY unrolled, tap-major (linear
    // in Wfrag), TWO-ahead A/B prefetch (rotation indices compile-time).
    f32x4 acc[4][4];
    #pragma unroll
    for (int g = 0; g < 4; ++g){
        #pragma unroll
        for (int mf = 0; mf < 4; ++mf) acc[g][mf] = (f32x4)0.0f;
    }

    const unsigned short* Abase = Xs + (size_t)(wm*XS_ROW + l15)*XS_CH + q*8;
    const unsigned short* Bbase = Wfrag + (size_t)wn*512 + lane*8;

    short8 a[3][4], bb[3][3], bO[3];
    #pragma unroll
    for (int p = 0; p < 2; ++p){                     // preload tc=0,1
        const int tap = p/3, cc = p%3;
        const int ky = tap/3, kx = tap%3;
        const int aoff = (ky*XS_ROW + kx)*XS_CH + cc*32;
        #pragma unroll
        for (int mf = 0; mf < 4; ++mf)
            a[p][mf] = *(const short8*)(Abase + aoff + mf*16*XS_CH);
        #pragma unroll
        for (int g = 0; g < 3; ++g)
            bb[p][g] = *(const short8*)(Bbase + p*8192 + g*2048);
    }

    #pragma unroll
    for (int tc = 0; tc < 27; ++tc){
        const int tap = tc/3;
        const int cur = tc % 3;
        if (tc + 2 < 27){
            const int ntc = tc + 2;
            const int nxt = ntc % 3;
            const int ntap = ntc/3, ncc = ntc%3;
            const int nky = ntap/3, nkx = ntap%3;
            const int aoff = (nky*XS_ROW + nkx)*XS_CH + ncc*32;  // const
            #pragma unroll
            for (int mf = 0; mf < 4; ++mf)
                a[nxt][mf] = *(const short8*)(Abase + aoff + mf*16*XS_CH);
            #pragma unroll
            for (int g = 0; g < 3; ++g)
                bb[nxt][g] = *(const short8*)(Bbase + ntc*8192 + g*2048);
        }
        if (tc >= 10 && tc <= 12)                    // o-gate frags for tc=12,13,14
            bO[tc-10] = *(const short8*)(Bbase + (tc+2)*8192 + 6144);
        if (tap == 4){  // o-gate: center tap only (ng=12+wn; covers bias ch)
            #pragma unroll
            for (int mf = 0; mf < 4; ++mf)
                acc[3][mf] = __builtin_amdgcn_mfma_f32_16x16x32_bf16(a[cur][mf], bO[tc-12], acc[3][mf], 0,0,0);
        }
        #pragma unroll
        for (int g = 0; g < 3; ++g){
            #pragma unroll
            for (int mf = 0; mf < 4; ++mf)
                acc[g][mf] = __builtin_amdgcn_mfma_f32_16x16x32_bf16(a[cur][mf], bb[cur][g], acc[g][mf], 0,0,0);
        }
    }

    // ---- epilogue: wave-local gates; c in place, channel-last
    const int o = wn*16 + l15;
    const int y = y0 + wm;
    #pragma unroll
    for (int mf = 0; mf < 4; ++mf){
        #pragma unroll
        for (int r = 0; r < 4; ++r){
            const int px = mf*16 + q*4 + r;
            const float fv = sigm_(acc[0][mf][r]);
            const float iv = sigm_(acc[1][mf][r]);
            const float gv = tanh_(acc[2][mf][r]);
            const float ov = sigm_(acc[3][mf][r]);
            const size_t cidx = (((size_t)(b*H_ + y)*W_ + px)*HID_ + o);
            const float cprev = t ? cbuf[cidx] : 0.0f;
            const float cn = cprev*fv + iv*gv;
            const float hn = tanh_(cn)*ov;
            if (t < T_-1){
                cbuf[cidx] = cn;
                hout[cidx] = f2bf(hn);
            } else {
                const size_t oidx = ((((size_t)(b*HID_ + o))*H_ + y)*W_ + px);
                out[oidx] = hn;
                out[CSTRIDE_ + oidx] = cn;
            }
        }
    }
}

extern "C" void kernel_launch(void* const* d_in, const int* in_sizes, int n_in,
                              void* d_out, int out_size, void* d_ws, size_t ws_size,
                              hipStream_t stream){
    const float* x  = (const float*)d_in[0];
    const float* Wf = (const float*)d_in[1];
    const float* bf = (const float*)d_in[2];
    const float* Wi = (const float*)d_in[3];
    const float* bi = (const float*)d_in[4];
    const float* Wc = (const float*)d_in[5];
    const float* bc = (const float*)d_in[6];
    const float* Wo = (const float*)d_in[7];
    const float* bo = (const float*)d_in[8];

    // ws: Wfrag 442368 | xbf 16777216 | cbuf 8388608 | hbfA 4194304 | hbfB 4194304
    unsigned short* Wfrag = (unsigned short*)d_ws;
    unsigned short* xbf   = (unsigned short*)((char*)d_ws + 442368);
    float*          cbuf  = (float*)((char*)d_ws + 442368 + 16777216);
    unsigned short* hbfA  = (unsigned short*)((char*)d_ws + 442368 + 16777216 + 8388608);
    unsigned short* hbfB  = hbfA + CSTRIDE_;

    prep_wfrag<<<dim3(864), dim3(256), 0, stream>>>(Wf, Wi, Wc, Wo, bf, bi, bc, bo, Wfrag);
    prep_xbf<<<dim3(2048), dim3(256), 0, stream>>>(x, xbf);

    for (int t = 0; t < T_; ++t){
        const unsigned short* hi = (t & 1) ? hbfA : hbfB;   // t==0 never reads
        unsigned short*       ho = (t & 1) ? hbfB : hbfA;
        lstm_step<<<dim3(256), dim3(512), 0, stream>>>(
            xbf, Wfrag, cbuf, hi, ho, (float*)d_out, t);
    }
}